// Round 13
// baseline (142.372 us; speedup 1.0000x reference)
//
#include <hip/hip_runtime.h>
#include <math.h>

#define B_ 16
#define N_ 4096
#define K_ 16
#define ALPHA_ 1.05f

#define NCHUNK 8             // j-chunks per point (one per wave-half)
#define CHUNK (N_ / NCHUNK)  // 512 j's per chunk
#define TJ 256               // j-tile staged in LDS per chunk
#define PTSB 32              // points per block
#define BLK 256              // 4 waves; lane<32 -> chunk 2w, lane>=32 -> 2w+1
#define SENT_F 60000.0f      // sentinel > any real sq-dist; f16-representable

typedef __fp16 h2 __attribute__((ext_vector_type(2)));

struct H2x4 { h2 v[4]; };    // view of one float4 = 8 fp16 = 4 h2 pairs

// ---------------------------------------------------------------------------
// Packed f16 ops (VOP3P) via inline asm (r8-proven codegen).
// ---------------------------------------------------------------------------
__device__ __forceinline__ h2 h2min(h2 a, h2 b) {
    unsigned int ua = __builtin_bit_cast(unsigned int, a);
    unsigned int ub = __builtin_bit_cast(unsigned int, b);
    unsigned int r;
    asm("v_pk_min_f16 %0, %1, %2" : "=v"(r) : "v"(ua), "v"(ub));
    return __builtin_bit_cast(h2, r);
}
__device__ __forceinline__ h2 h2max(h2 a, h2 b) {
    unsigned int ua = __builtin_bit_cast(unsigned int, a);
    unsigned int ub = __builtin_bit_cast(unsigned int, b);
    unsigned int r;
    asm("v_pk_max_f16 %0, %1, %2" : "=v"(r) : "v"(ua), "v"(ub));
    return __builtin_bit_cast(h2, r);
}
__device__ __forceinline__ h2 h2add(h2 a, h2 b) {
    unsigned int ua = __builtin_bit_cast(unsigned int, a);
    unsigned int ub = __builtin_bit_cast(unsigned int, b);
    unsigned int r;
    asm("v_pk_add_f16 %0, %1, %2" : "=v"(r) : "v"(ua), "v"(ub));
    return __builtin_bit_cast(h2, r);
}
__device__ __forceinline__ h2 h2mul(h2 a, h2 b) {
    unsigned int ua = __builtin_bit_cast(unsigned int, a);
    unsigned int ub = __builtin_bit_cast(unsigned int, b);
    unsigned int r;
    asm("v_pk_mul_f16 %0, %1, %2" : "=v"(r) : "v"(ua), "v"(ub));
    return __builtin_bit_cast(h2, r);
}
__device__ __forceinline__ h2 h2fma(h2 a, h2 b, h2 c) {
    unsigned int ua = __builtin_bit_cast(unsigned int, a);
    unsigned int ub = __builtin_bit_cast(unsigned int, b);
    unsigned int uc = __builtin_bit_cast(unsigned int, c);
    unsigned int r;
    asm("v_pk_fma_f16 %0, %1, %2, %3" : "=v"(r) : "v"(ua), "v"(ub), "v"(uc));
    return __builtin_bit_cast(h2, r);
}

// ---------------------------------------------------------------------------
// Batcher odd-even merge sort, n=16, ascending: 63 CE, 2 streams per instr.
// ---------------------------------------------------------------------------
__device__ __forceinline__ void oems_sort16h(h2 v[16]) {
#pragma unroll
    for (int p = 1; p < 16; p <<= 1) {
#pragma unroll
        for (int k = p; k >= 1; k >>= 1) {
#pragma unroll
            for (int j = k & (p - 1); j + k < 16; j += 2 * k) {
#pragma unroll
                for (int i = 0; i < k; ++i) {
                    if (i + j + k < 16 &&
                        ((i + j) / (2 * p)) == ((i + j + k) / (2 * p))) {
                        const h2 a = v[i + j], b = v[i + j + k];
                        v[i + j]     = h2min(a, b);
                        v[i + j + k] = h2max(a, b);
                    }
                }
            }
        }
    }
}

// knn (sorted asc, packed) := lowest 16 of {knn, c} per half; c sorted asc.
__device__ __forceinline__ void merge16h(h2 knn[16], const h2 c[16]) {
#pragma unroll
    for (int i = 0; i < 16; ++i) knn[i] = h2min(knn[i], c[15 - i]);
#pragma unroll
    for (int j = 8; j > 0; j >>= 1) {
#pragma unroll
        for (int i = 0; i < 16; ++i) {
            const int l = i ^ j;
            if (l > i) {
                const h2 a = knn[i], b = knn[l];
                knn[i] = h2min(a, b);
                knn[l] = h2max(a, b);
            }
        }
    }
}

// f32 merge for the once-per-lane lo/hi combine (both sorted asc).
__device__ __forceinline__ void merge16f(float knn[16], const float c[16]) {
#pragma unroll
    for (int i = 0; i < 16; ++i) knn[i] = fminf(knn[i], c[15 - i]);
#pragma unroll
    for (int j = 8; j > 0; j >>= 1) {
#pragma unroll
        for (int i = 0; i < 16; ++i) {
            const int l = i ^ j;
            if (l > i) {
                const float a = knn[i], b = knn[l];
                knn[i] = fminf(a, b);
                knn[l] = fmaxf(a, b);
            }
        }
    }
}

// ---------------------------------------------------------------------------
// Process one 256-j f16-SoA tile (coords NEGATED): 8 batches of 32 j.
// xs4/ys4/zs4 are PER-LANE tile bases (2 distinct addrs per wave -> 2-way
// LDS broadcast, free). jg0 is per-lane.
// ---------------------------------------------------------------------------
template <bool HAS_SELF>
__device__ __forceinline__ void process_tile(const float4* xs4,
                                             const float4* ys4,
                                             const float4* zs4,
                                             int jg0, int i,
                                             h2 qx, h2 qy, h2 qz,
                                             h2 knn[16]) {
#pragma unroll 2
    for (int bb = 0; bb < TJ / 32; ++bb) {
        h2 c[16];
#pragma unroll
        for (int r = 0; r < 4; ++r) {
            const H2x4 hx = __builtin_bit_cast(H2x4, xs4[bb * 4 + r]);
            const H2x4 hy = __builtin_bit_cast(H2x4, ys4[bb * 4 + r]);
            const H2x4 hz = __builtin_bit_cast(H2x4, zs4[bb * 4 + r]);
#pragma unroll
            for (int t = 0; t < 4; ++t) {
                const h2 dx = h2add(qx, hx.v[t]);
                const h2 dy = h2add(qy, hy.v[t]);
                const h2 dz = h2add(qz, hz.v[t]);
                h2 d = h2mul(dx, dx);
                d = h2fma(dy, dy, d);
                d = h2fma(dz, dz, d);
                if (HAS_SELF) {
                    const int j0 = jg0 + bb * 32 + r * 8 + 2 * t;
                    if (j0 == i)     d.x = (__fp16)SENT_F;
                    if (j0 + 1 == i) d.y = (__fp16)SENT_F;
                }
                c[r * 4 + t] = d;
            }
        }
        oems_sort16h(c);
        merge16h(knn, c);
    }
}

// ---------------------------------------------------------------------------
// Kernel 1: per-point mean of 16 smallest non-self squared distances.
// Grid 2048 blocks (32 points each) -> 8 blocks/CU -> 8 waves/SIMD (tests the
// issue-cadence starvation theory). Block = 256 thr = 4 waves; lane<32 works
// chunk 2w, lane>=32 chunk 2w+1 (512 j each). LDS exactly 20 KB.
// ---------------------------------------------------------------------------
__global__ __launch_bounds__(BLK, 8) void knn_kernel(const float* __restrict__ pcs,
                                                     float* __restrict__ knn_out) {
    __shared__ float4 tile[NCHUNK][3][TJ / 8];   // f16 SoA x/y/z, 12 KB
    __shared__ __fp16 lst[NCHUNK][PTSB][K_];     // 8 KB, no pad (capped merge)

    const int b    = blockIdx.x >> 7;            // 128 groups per batch
    const int grp  = blockIdx.x & 127;
    const int i0   = grp * PTSB;
    const int lane = threadIdx.x & 63;
    const int w    = threadIdx.x >> 6;           // 0..3
    const int sub  = lane >> 5;                  // 0/1: which chunk of the pair
    const int pl   = lane & 31;                  // point-lane 0..31
    const int cl   = 2 * w + sub;                // this lane's chunk 0..7

    const float* __restrict__ src = pcs + (size_t)b * N_ * 3;

    const int i  = i0 + pl;
    const __fp16 qxh = (__fp16)src[3 * i + 0];   // RTN, same grid as candidates
    const __fp16 qyh = (__fp16)src[3 * i + 1];
    const __fp16 qzh = (__fp16)src[3 * i + 2];
    const h2 qx = {qxh, qxh}, qy = {qyh, qyh}, qz = {qzh, qzh};

    const h2 sent = {(__fp16)SENT_F, (__fp16)SENT_F};
    h2 knn[K_];
#pragma unroll
    for (int t = 0; t < K_; ++t) knn[t] = sent;

    h2* tx = (h2*)&tile[cl][0][0];
    h2* ty = (h2*)&tile[cl][1][0];
    h2* tz = (h2*)&tile[cl][2][0];
    const float4* xs4 = &tile[cl][0][0];
    const float4* ys4 = &tile[cl][1][0];
    const float4* zs4 = &tile[cl][2][0];

#pragma unroll 1
    for (int t0 = 0; t0 < CHUNK; t0 += TJ) {
        const int jg0 = cl * CHUNK + t0;         // per-lane tile base (j index)

        // ---- stage: each lane stages 8 points of ITS chunk's tile
        //      (lanes 0-31 fill tile[2w], 32-63 fill tile[2w+1]).
        const float4* __restrict__ g4 =
            (const float4*)(src + (size_t)(jg0 + pl * 8) * 3);
        const float4 f0 = g4[0], f1 = g4[1], f2 = g4[2];
        const float4 f3 = g4[3], f4 = g4[4], f5 = g4[5];
        tx[4 * pl + 0] = h2{(__fp16)(-f0.x), (__fp16)(-f0.w)};
        tx[4 * pl + 1] = h2{(__fp16)(-f1.z), (__fp16)(-f2.y)};
        tx[4 * pl + 2] = h2{(__fp16)(-f3.x), (__fp16)(-f3.w)};
        tx[4 * pl + 3] = h2{(__fp16)(-f4.z), (__fp16)(-f5.y)};
        ty[4 * pl + 0] = h2{(__fp16)(-f0.y), (__fp16)(-f1.x)};
        ty[4 * pl + 1] = h2{(__fp16)(-f1.w), (__fp16)(-f2.z)};
        ty[4 * pl + 2] = h2{(__fp16)(-f3.y), (__fp16)(-f4.x)};
        ty[4 * pl + 3] = h2{(__fp16)(-f4.w), (__fp16)(-f5.z)};
        tz[4 * pl + 0] = h2{(__fp16)(-f0.z), (__fp16)(-f1.y)};
        tz[4 * pl + 1] = h2{(__fp16)(-f2.x), (__fp16)(-f2.w)};
        tz[4 * pl + 2] = h2{(__fp16)(-f3.z), (__fp16)(-f4.y)};
        tz[4 * pl + 3] = h2{(__fp16)(-f5.x), (__fp16)(-f5.w)};
        // wave stages exactly the tiles it reads; lanes lockstep within the
        // wave, compiler inserts lgkmcnt waits (may-alias). No barrier.

        // HAS_SELF wave-uniform: does tile A (chunk 2w) or B (2w+1) at this
        // t0 cover the block's 256-window?
        const int winA = 4 * w + (t0 >> 8);
        const int winB = winA + 2;
        const int wi   = i0 >> 8;
        if (wi == winA || wi == winB) {
            process_tile<true >(xs4, ys4, zs4, jg0, i, qx, qy, qz, knn);
        } else {
            process_tile<false>(xs4, ys4, zs4, jg0, i, qx, qy, qz, knn);
        }
    }

    // ---- combine the two packed streams (lo/hi), per lane
    float lo[K_], hi[K_];
#pragma unroll
    for (int t = 0; t < K_; ++t) { lo[t] = (float)knn[t].x; hi[t] = (float)knn[t].y; }
    merge16f(lo, hi);   // lowest 16 of 32, sorted asc (values exact f16)

#pragma unroll
    for (int q = 0; q < K_; ++q) lst[cl][pl][q] = (__fp16)lo[q];
    __syncthreads();

    // ---- 8-way merge of sorted 16-lists, one thread per point
    if (threadIdx.x < PTSB) {
        const int p = threadIdx.x;
        int p0 = 0, p1 = 0, p2 = 0, p3 = 0, p4 = 0, p5 = 0, p6 = 0, p7 = 0;
        float m0 = (float)lst[0][p][0], m1 = (float)lst[1][p][0];
        float m2 = (float)lst[2][p][0], m3 = (float)lst[3][p][0];
        float m4 = (float)lst[4][p][0], m5 = (float)lst[5][p][0];
        float m6 = (float)lst[6][p][0], m7 = (float)lst[7][p][0];
        float sm = 0.0f;
#pragma unroll
        for (int st = 0; st < K_; ++st) {
            const float m = fminf(fminf(fminf(m0, m1), fminf(m2, m3)),
                                  fminf(fminf(m4, m5), fminf(m6, m7)));
            sm += m;
            if (m0 == m)      { ++p0; m0 = (p0 < K_) ? (float)lst[0][p][p0] : SENT_F; }
            else if (m1 == m) { ++p1; m1 = (p1 < K_) ? (float)lst[1][p][p1] : SENT_F; }
            else if (m2 == m) { ++p2; m2 = (p2 < K_) ? (float)lst[2][p][p2] : SENT_F; }
            else if (m3 == m) { ++p3; m3 = (p3 < K_) ? (float)lst[3][p][p3] : SENT_F; }
            else if (m4 == m) { ++p4; m4 = (p4 < K_) ? (float)lst[4][p][p4] : SENT_F; }
            else if (m5 == m) { ++p5; m5 = (p5 < K_) ? (float)lst[5][p][p5] : SENT_F; }
            else if (m6 == m) { ++p6; m6 = (p6 < K_) ? (float)lst[6][p][p6] : SENT_F; }
            else              { ++p7; m7 = (p7 < K_) ? (float)lst[7][p][p7] : SENT_F; }
        }
        knn_out[(size_t)b * N_ + i0 + p] = sm * (1.0f / (float)K_);
    }
}

// ---------------------------------------------------------------------------
// Block reduction helper (256 threads = 4 waves)
// ---------------------------------------------------------------------------
__device__ __forceinline__ float block_reduce_sum_256(float v, float* sbuf) {
    const int lane = threadIdx.x & 63;
    const int w    = threadIdx.x >> 6;
#pragma unroll
    for (int o = 32; o > 0; o >>= 1) v += __shfl_down(v, o, 64);
    __syncthreads();
    if (lane == 0) sbuf[w] = v;
    __syncthreads();
    return sbuf[0] + sbuf[1] + sbuf[2] + sbuf[3];
}

// ---------------------------------------------------------------------------
// Kernel 2: per-batch mean, std (two-pass), threshold, penalty partial sum,
// fused final: atomicAdd of scaled penalty into out[0] (memset to 0 first).
// ---------------------------------------------------------------------------
__global__ __launch_bounds__(256) void stats_kernel(const float* __restrict__ knn_d,
                                                    float* __restrict__ out) {
    const int b   = blockIdx.x;
    const int tid = threadIdx.x;
    const float* __restrict__ x = knn_d + (size_t)b * N_;

    __shared__ float sbuf[4];

    float v[16];
    float s = 0.0f;
#pragma unroll
    for (int t = 0; t < 16; ++t) {
        v[t] = x[tid + t * 256];
        s += v[t];
    }
    const float total = block_reduce_sum_256(s, sbuf);
    const float mu = total * (1.0f / (float)N_);

    float vs = 0.0f;
#pragma unroll
    for (int t = 0; t < 16; ++t) {
        const float d = v[t] - mu;
        vs += d * d;
    }
    const float var    = block_reduce_sum_256(vs, sbuf) * (1.0f / (float)N_);
    const float thresh = mu + ALPHA_ * sqrtf(var);

    float p = 0.0f;
#pragma unroll
    for (int t = 0; t < 16; ++t) {
        if (v[t] > thresh) p += v[t];
    }
    const float psum = block_reduce_sum_256(p, sbuf);
    if (tid == 0) atomicAdd(out, psum * (1.0f / (float)(B_ * N_)));
}

extern "C" void kernel_launch(void* const* d_in, const int* in_sizes, int n_in,
                              void* d_out, int out_size, void* d_ws, size_t ws_size,
                              hipStream_t stream) {
    const float* pcs = (const float*)d_in[0];
    float* out = (float*)d_out;

    float* knn_d = (float*)d_ws;             // B*N floats = 256 KB

    (void)hipMemsetAsync(out, 0, sizeof(float), stream);
    knn_kernel<<<B_ * (N_ / PTSB), BLK, 0, stream>>>(pcs, knn_d);
    stats_kernel<<<B_, 256, 0, stream>>>(knn_d, out);
}